// Round 1
// 262.475 us; speedup vs baseline: 1.0170x; 1.0170x over previous
//
#include <hip/hip_runtime.h>
#include <hip/hip_bf16.h>

// MyGNN on MI355X — round 6.
//  prep: zero counts + convert W1/Wfi/W2/Wl -> frag-ordered bf16 (once, not per-block)
//  K1 (fused): fill_buckets ∪ gemm1(x1@W1->t_bf) ∪ branch0(gather x0 @Wfi -> out)
//  agg1: h1 = A@t1 + b1 (bf16 out)
//  gemm2: t2 = h1@W2 (bf16 out)
//  agg2_sel: sel[m] = b2 + A-row(node(m)) @ t2   (only M selected rows, bf16 out)
//  br1: out1 = sel@Wl + bl
// All GEMMs: mfma_f32_16x16x32_bf16, fp32 accumulate. LDS per gemm block: 16 KB
// (two-half B staging), staging is a straight 16B-vector copy of preconverted W.

#define B_    64
#define ADJ_  1000
#define N_    64000
#define E_    (1 << 20)
#define M_    32000
#define DV    128
#define CAP   64
#define RANGES 8
#define RSPAN  (N_ / RANGES)   // 8000
#define CHUNKS 512
#define EPB    (E_ / CHUNKS)   // 2048

typedef __attribute__((ext_vector_type(8))) short short8v;   // 8 bf16
typedef __attribute__((ext_vector_type(4))) float float4v;

__device__ __forceinline__ float u2f(unsigned int u) {
  union { unsigned int i; float f; } x; x.i = u; return x.f;
}
__device__ __forceinline__ unsigned short f2bf(float f) {   // RNE
  union { float f; unsigned int i; } x; x.f = f;
  unsigned int r = x.i + 0x7fffu + ((x.i >> 16) & 1u);
  return (unsigned short)(r >> 16);
}
__device__ __forceinline__ unsigned int pack_bf2(float a, float b) {
  __hip_bfloat162 h = __float22bfloat162_rn(float2{a, b});
  union { __hip_bfloat162 h; unsigned int u; } c; c.h = h;
  return c.u;
}

// ---------------- prep: counts=0 + W -> frag-ordered bf16 ----------------
// Layout (must match gemm_tile's B-frag read):
//   W[k][n] -> Wbf[ ((((n>>4)*4+(k>>5))*64 + ((k>>3)&3)*16 + (n&15)) << 3) + (k&7) ]
// so that frag(nb,kc,lane)[j] = Wbf[ ((nb*4+kc)*64+lane)*8 + j ]
//                             = W[kc*32 + (lane>>4)*8 + j][nb*16 + (lane&15)].
__global__ __launch_bounds__(256)
void prep_k(const float* __restrict__ W1, const float* __restrict__ Wfi,
            const float* __restrict__ W2, const float* __restrict__ Wl,
            unsigned short* __restrict__ Wbf, int* __restrict__ counts) {
  int b = blockIdx.x, t = threadIdx.x;
  int mi = b >> 3;                                    // 4 matrices x 8 blocks
  const float* W = (mi == 0) ? W1 : (mi == 1) ? Wfi : (mi == 2) ? W2 : Wl;
  unsigned short* out = Wbf + mi * 16384;
  int base = (b & 7) * 2048 + t * 8;
  float4 f0 = *(const float4*)(W + base);
  float4 f1 = *(const float4*)(W + base + 4);
  float v[8] = {f0.x, f0.y, f0.z, f0.w, f1.x, f1.y, f1.z, f1.w};
#pragma unroll
  for (int u = 0; u < 8; u++) {
    int g = base + u;
    int k = g >> 7, n = g & 127;
    int addr = ((((n >> 4) * 4 + (k >> 5)) * 64 + ((k >> 3) & 3) * 16 + (n & 15)) << 3)
             + (k & 7);
    out[addr] = f2bf(v[u]);
  }
  for (int i = b * 256 + t; i < N_; i += 32 * 256) counts[i] = 0;
}

// ---------------- fill part (device fn): chunk c, dst-range r ----------------
__device__ __forceinline__ void fill_part(const int* __restrict__ ei,
                                          int* __restrict__ counts,
                                          unsigned short* __restrict__ bucket,
                                          int c, int r) {
  const int* srcA = ei;
  const int* dstA = ei + E_;
  int lo = r * RSPAN;
  int t4 = c * EPB + (int)threadIdx.x * 4;
  int4 d0 = *(const int4*)(dstA + t4);
  int4 s0 = *(const int4*)(srcA + t4);
  int4 d1 = *(const int4*)(dstA + t4 + 1024);
  int4 s1 = *(const int4*)(srcA + t4 + 1024);
#define PROC(D, S) do {                                                \
    if ((unsigned)((D) - lo) < (unsigned)RSPAN) {                      \
      int pos = atomicAdd(&counts[(D)], 1);                            \
      if (pos < CAP) bucket[(D) * CAP + pos] = (unsigned short)(S);    \
    } } while (0)
  PROC(d0.x, s0.x); PROC(d0.y, s0.y); PROC(d0.z, s0.z); PROC(d0.w, s0.w);
  PROC(d1.x, s1.x); PROC(d1.y, s1.y); PROC(d1.z, s1.z); PROC(d1.w, s1.w);
#undef PROC
}

// ---------------- MFMA GEMM tile (device fn) ----------------
// tile = 64 rows; 4 waves x 16-row stripes; B pre-converted frag-ordered bf16.
// Two-half staging: 16 KB LDS; half-1 global loads overlap half-0 MFMAs.
// C/D: col = lane&15, row = (lane>>4)*4 + reg.
template<bool GATHER, bool ABF16, bool OUTBF16, bool HASBIAS>
__device__ __forceinline__ void gemm_tile(const void* __restrict__ in,
                                          const unsigned short* __restrict__ Wbf,
                                          const float* __restrict__ bias,
                                          void* __restrict__ out_, int tile,
                                          const int* __restrict__ bidx,
                                          const int* __restrict__ nidx,
                                          unsigned short* __restrict__ Bs) {
  int tid  = threadIdx.x;
  int lane = tid & 63;
  int wv   = tid >> 6;
  int m    = lane & 15;
  int q    = lane >> 4;
  int rbase = tile * 64 + wv * 16;
  int r     = rbase + m;

  const short8v* Wv  = (const short8v*)Wbf;   // 2048 vecs (32 KB)
  short8v*       Bsv = (short8v*)Bs;          // 1024 vecs (16 KB)

  // issue half-0 B loads (L2-resident, coalesced 16B/lane)
  short8v w[4];
#pragma unroll
  for (int i = 0; i < 4; i++) w[i] = Wv[tid + i * 256];

  size_t ir;
  if (GATHER) ir = (size_t)bidx[r] * ADJ_ + nidx[r];
  else        ir = (size_t)r;

  short8v af[4];
  if (ABF16) {
    const unsigned short* arow = (const unsigned short*)in + ir * DV;
#pragma unroll
    for (int kc = 0; kc < 4; kc++)
      af[kc] = *(const short8v*)(arow + kc * 32 + q * 8);
  } else {
    const float* arow = (const float*)in + ir * DV;
#pragma unroll
    for (int kc = 0; kc < 4; kc++) {
      const float4* p = (const float4*)(arow + kc * 32 + q * 8);
      float4 f0 = p[0], f1 = p[1];
      union { short8v s; unsigned int u[4]; } t;
      t.u[0] = pack_bf2(f0.x, f0.y);
      t.u[1] = pack_bf2(f0.z, f0.w);
      t.u[2] = pack_bf2(f1.x, f1.y);
      t.u[3] = pack_bf2(f1.z, f1.w);
      af[kc] = t.s;
    }
  }

#pragma unroll
  for (int i = 0; i < 4; i++) Bsv[tid + i * 256] = w[i];
  __syncthreads();

  float4v acc[8];
#pragma unroll
  for (int nb = 0; nb < 8; nb++) acc[nb] = (float4v){0.f, 0.f, 0.f, 0.f};

  // issue half-1 B loads now; they complete under the half-0 MFMAs
#pragma unroll
  for (int i = 0; i < 4; i++) w[i] = Wv[1024 + tid + i * 256];

#pragma unroll
  for (int nb = 0; nb < 4; nb++)
#pragma unroll
    for (int kc = 0; kc < 4; kc++) {
      short8v bf = Bsv[(nb * 4 + kc) * 64 + lane];
      acc[nb] = __builtin_amdgcn_mfma_f32_16x16x32_bf16(af[kc], bf, acc[nb], 0, 0, 0);
    }
  __syncthreads();
#pragma unroll
  for (int i = 0; i < 4; i++) Bsv[tid + i * 256] = w[i];
  __syncthreads();
#pragma unroll
  for (int nb = 4; nb < 8; nb++)
#pragma unroll
    for (int kc = 0; kc < 4; kc++) {
      short8v bf = Bsv[((nb - 4) * 4 + kc) * 64 + lane];
      acc[nb] = __builtin_amdgcn_mfma_f32_16x16x32_bf16(af[kc], bf, acc[nb], 0, 0, 0);
    }

#pragma unroll
  for (int nb = 0; nb < 8; nb++) {
    float bvn = HASBIAS ? bias[nb * 16 + m] : 0.f;
    int col = nb * 16 + m;
#pragma unroll
    for (int i = 0; i < 4; i++) {
      int row = rbase + q * 4 + i;
      float v = acc[nb][i] + bvn;
      if (OUTBF16) ((unsigned short*)out_)[(size_t)row * DV + col] = f2bf(v);
      else         ((float*)out_)[(size_t)row * DV + col] = v;
    }
  }
}

// ---------------- K1: fused fill + gemm1 + branch0 ----------------
// Period-16 block pattern: rem 0..7 -> fill (range=rem == blockIdx%8 for XCD
// L2 locality), rem 8..15 -> o = g*8+rem-8: o<1000 gemm1 tile, o<1500 br0 tile.
__global__ __launch_bounds__(256)
void k1_fused(const int* __restrict__ ei, int* __restrict__ counts,
              unsigned short* __restrict__ bucket,
              const float* __restrict__ x1, const unsigned short* __restrict__ Wbf,
              unsigned int* __restrict__ t_bf,
              const float* __restrict__ x0, const float* __restrict__ bfi,
              float* __restrict__ out0,
              const int* __restrict__ b0, const int* __restrict__ n0i) {
  __shared__ unsigned short Bs[8192];   // 16 KB
  int g = blockIdx.x >> 4, rem = blockIdx.x & 15;
  if (rem < 8) { fill_part(ei, counts, bucket, g, rem); return; }
  int o = g * 8 + rem - 8;
  if (o < 1000)
    gemm_tile<false, false, true, false>(x1, Wbf, nullptr, t_bf, o, nullptr, nullptr, Bs);
  else if (o < 1500)
    gemm_tile<true, false, false, true>(x0, Wbf + 16384, bfi, out0, o - 1000, b0, n0i, Bs);
}

// ---------------- standalone GEMM ----------------
template<bool GATHER, bool ABF16, bool OUTBF16, bool HASBIAS>
__global__ __launch_bounds__(256)
void gemm_k(const void* __restrict__ in, const unsigned short* __restrict__ Wbf,
            const float* __restrict__ bias, void* __restrict__ out_,
            const int* __restrict__ bidx, const int* __restrict__ nidx) {
  __shared__ unsigned short Bs[8192];
  gemm_tile<GATHER, ABF16, OUTBF16, HASBIAS>(in, Wbf, bias, out_, blockIdx.x, bidx, nidx, Bs);
}

// ---------------- aggregation: one wave per row ----------------
// SEL=false: row w = node id (w<N_). SEL=true: row w = output slot, node from
// (bidx,nidx) (w<M_). out row = bias + sum of x[src,:], bf16 or f32.
template<bool OUTBF16, bool SEL>
__global__ __launch_bounds__(256)
void aggregate_k(const unsigned int* __restrict__ x,   // bf16x2 rows [N,64]
                 const int* __restrict__ counts,
                 const unsigned short* __restrict__ bucket,
                 const float* __restrict__ bias, void* __restrict__ out_,
                 const int* __restrict__ bidx, const int* __restrict__ nidx) {
  int w    = (blockIdx.x * 256 + threadIdx.x) >> 6;
  int lane = threadIdx.x & 63;
  int node = SEL ? (bidx[w] * ADJ_ + nidx[w]) : w;
  int cnt = counts[node]; cnt = min(cnt, CAP);
  int mysrc = (int)bucket[node * CAP + lane];
  float2 bv = ((const float2*)bias)[lane];
  float2 acc; acc.x = bv.x; acc.y = bv.y;

  int d = 0;
  for (; d + 8 <= cnt; d += 8) {     // 8 outstanding gathers for MLP
    int s0 = __shfl(mysrc, d,     64);
    int s1 = __shfl(mysrc, d + 1, 64);
    int s2 = __shfl(mysrc, d + 2, 64);
    int s3 = __shfl(mysrc, d + 3, 64);
    int s4 = __shfl(mysrc, d + 4, 64);
    int s5 = __shfl(mysrc, d + 5, 64);
    int s6 = __shfl(mysrc, d + 6, 64);
    int s7 = __shfl(mysrc, d + 7, 64);
    unsigned int u0 = x[(size_t)s0 * 64 + lane];
    unsigned int u1 = x[(size_t)s1 * 64 + lane];
    unsigned int u2 = x[(size_t)s2 * 64 + lane];
    unsigned int u3 = x[(size_t)s3 * 64 + lane];
    unsigned int u4 = x[(size_t)s4 * 64 + lane];
    unsigned int u5 = x[(size_t)s5 * 64 + lane];
    unsigned int u6 = x[(size_t)s6 * 64 + lane];
    unsigned int u7 = x[(size_t)s7 * 64 + lane];
    acc.x += ((u2f(u0 << 16) + u2f(u1 << 16)) + (u2f(u2 << 16) + u2f(u3 << 16)))
           + ((u2f(u4 << 16) + u2f(u5 << 16)) + (u2f(u6 << 16) + u2f(u7 << 16)));
    acc.y += ((u2f(u0 & 0xffff0000u) + u2f(u1 & 0xffff0000u))
            + (u2f(u2 & 0xffff0000u) + u2f(u3 & 0xffff0000u)))
           + ((u2f(u4 & 0xffff0000u) + u2f(u5 & 0xffff0000u))
            + (u2f(u6 & 0xffff0000u) + u2f(u7 & 0xffff0000u)));
  }
  if (d + 4 <= cnt) {
    int s0 = __shfl(mysrc, d,     64);
    int s1 = __shfl(mysrc, d + 1, 64);
    int s2 = __shfl(mysrc, d + 2, 64);
    int s3 = __shfl(mysrc, d + 3, 64);
    unsigned int u0 = x[(size_t)s0 * 64 + lane];
    unsigned int u1 = x[(size_t)s1 * 64 + lane];
    unsigned int u2 = x[(size_t)s2 * 64 + lane];
    unsigned int u3 = x[(size_t)s3 * 64 + lane];
    acc.x += (u2f(u0 << 16) + u2f(u1 << 16)) + (u2f(u2 << 16) + u2f(u3 << 16));
    acc.y += (u2f(u0 & 0xffff0000u) + u2f(u1 & 0xffff0000u))
           + (u2f(u2 & 0xffff0000u) + u2f(u3 & 0xffff0000u));
    d += 4;
  }
  for (; d < cnt; d++) {
    int s = __shfl(mysrc, d, 64);
    unsigned int u = x[(size_t)s * 64 + lane];
    acc.x += u2f(u << 16);
    acc.y += u2f(u & 0xffff0000u);
  }
  if (OUTBF16) ((unsigned int*)out_)[(size_t)w * 64 + lane] = pack_bf2(acc.x, acc.y);
  else         ((float2*)out_)[(size_t)w * 64 + lane] = acc;
}

extern "C" void kernel_launch(void* const* d_in, const int* in_sizes, int n_in,
                              void* d_out, int out_size, void* d_ws, size_t ws_size,
                              hipStream_t stream) {
  const float* x0  = (const float*)d_in[0];
  const float* x1  = (const float*)d_in[1];
  const int*   ei  = (const int*)  d_in[2];
  const int*   b0  = (const int*)  d_in[3];
  const int*   n0i = (const int*)  d_in[4];
  const int*   b1  = (const int*)  d_in[5];
  const int*   n1i = (const int*)  d_in[6];
  const float* W1  = (const float*)d_in[7];
  const float* bb1 = (const float*)d_in[8];
  const float* W2  = (const float*)d_in[9];
  const float* bb2 = (const float*)d_in[10];
  const float* Wl  = (const float*)d_in[11];
  const float* bl  = (const float*)d_in[12];
  const float* Wfi = (const float*)d_in[13];
  const float* bfi = (const float*)d_in[14];
  float* out = (float*)d_out;

  // ws: t_bf 16MB | h_bf 16MB | sel_bf 8MB | counts 256KB | bucket 8MB | Wbf 128KB
  unsigned int*   t_bf   = (unsigned int*)d_ws;
  unsigned int*   h_bf   = t_bf + (size_t)N_ * 64;
  unsigned int*   sel_bf = h_bf + (size_t)N_ * 64;
  int*            counts = (int*)(sel_bf + (size_t)M_ * 64);
  unsigned short* bucket = (unsigned short*)(counts + N_);
  unsigned short* Wbf    = bucket + (size_t)N_ * CAP;   // 4 x 16384 bf16

  // prep: counts=0 + all four W -> frag-ordered bf16 (replaces memset dispatch)
  prep_k<<<32, 256, 0, stream>>>(W1, Wfi, W2, Wl, Wbf, counts);

  // K1: fill_buckets ∪ t1=x1@W1 ∪ out0=gather(x0)@Wfi+bfi
  k1_fused<<<512 * 16, 256, 0, stream>>>(ei, counts, bucket, x1, Wbf, t_bf,
                                         x0, bfi, out, b0, n0i);

  // h1 = A@t1 + b1  (bf16 out)
  aggregate_k<true, false><<<N_ / 4, 256, 0, stream>>>(t_bf, counts, bucket, bb1,
                                                       h_bf, nullptr, nullptr);
  // t2 = h1@W2  (bf16 out)
  gemm_k<false, true, true, false><<<N_ / 64, 256, 0, stream>>>(h_bf, Wbf + 2 * 16384,
                                                                nullptr, t_bf,
                                                                nullptr, nullptr);
  // sel[m] = b2 + sum_{src in bucket(node(m))} t2[src]  (bf16 out)
  aggregate_k<true, true><<<M_ / 4, 256, 0, stream>>>(t_bf, counts, bucket, bb2,
                                                      sel_bf, b1, n1i);
  // out1 = sel@Wl + bl  (f32 out)
  gemm_k<false, true, false, true><<<M_ / 64, 256, 0, stream>>>(sel_bf, Wbf + 3 * 16384,
                                                                bl, out + (size_t)M_ * DV,
                                                                nullptr, nullptr);
}